// Round 11
// baseline (99.392 us; speedup 1.0000x reference)
//
#include <hip/hip_runtime.h>
#include <hip/hip_bf16.h>

typedef __attribute__((ext_vector_type(4))) float  f4;
typedef __attribute__((ext_vector_type(8))) short  short8;
typedef __attribute__((ext_vector_type(4))) float  f32x4;

static constexpr int NHEAD = 16;
static constexpr int NIN   = 128;
static constexpr int NOUT  = 128;
static constexpr int NROWS = 8 * 2048;          // B*S = 16384
static constexpr int RSTR  = NHEAD * NIN;       // 2048 floats per (b,s) row
static constexpr int TILES = 8;                 // tiles of 64 rows (4 waves x 16)
static constexpr int ROWS_PER_BLOCK = 64 * TILES;         // 512 rows per WG
static constexpr int BLOCKS_X = NROWS / ROWS_PER_BLOCK;   // 32 -> grid 32x16 = 512 WGs
// 256-thr WGs: LDS-capped 5 WGs/CU (5x32KB = 160KB) = 20 waves/CU residency,
// same staging amortization as the 52.3us R6 config (512 rows/WG).

static __device__ inline unsigned short f2bfu(float f) {
  union { __hip_bfloat16 h; unsigned short u; } v;
  v.h = __float2bfloat16(f);
  return v.u;
}

static __device__ inline short8 cvt8(f4 a, f4 b) {
  short8 r;
  r[0] = (short)f2bfu(a[0]); r[1] = (short)f2bfu(a[1]);
  r[2] = (short)f2bfu(a[2]); r[3] = (short)f2bfu(a[3]);
  r[4] = (short)f2bfu(b[0]); r[5] = (short)f2bfu(b[1]);
  r[6] = (short)f2bfu(b[2]); r[7] = (short)f2bfu(b[3]);
  return r;
}

__global__ __launch_bounds__(256, 5)   // 5 WGs/CU target -> VGPR cap 102
void bdp_kernel(const float* __restrict__ X, const float* __restrict__ W,
                float* __restrict__ O) {
  // W(head) bf16 MFMA A-fragments, fragment-contiguous (0 bank conflicts):
  // frag = n*4 + kk; lane holds o = n*16 + (lane&15), k = kk*32 + (lane>>4)*8 + j.
  __shared__ short8 wtile[32][64];

  const int head = blockIdx.y;
  const int tid  = (int)threadIdx.x;
  const int lane = tid & 63;
  const int wid  = tid >> 6;      // 4 waves
  const int lr   = lane & 15;
  const int lq   = lane >> 4;

  const int rowbase = (int)blockIdx.x * ROWS_PER_BLOCK + wid * 16;
  const float* xr = X + (size_t)(rowbase + lr) * RSTR + head * NIN;

  // ---- issue tiles 0,1 X loads before W staging (best-effort overlap) ----
  f4 xs0[8], xs1[8];              // two named slots, static indexing
  #pragma unroll
  for (int kk = 0; kk < 4; ++kk) {
    const int koff = kk * 32 + lq * 8;
    xs0[2*kk]   = *reinterpret_cast<const f4*>(xr + koff);
    xs0[2*kk+1] = *reinterpret_cast<const f4*>(xr + koff + 4);
  }
  {
    const float* xr1 = xr + (size_t)64 * RSTR;
    #pragma unroll
    for (int kk = 0; kk < 4; ++kk) {
      const int koff = kk * 32 + lq * 8;
      xs1[2*kk]   = *reinterpret_cast<const f4*>(xr1 + koff);
      xs1[2*kk+1] = *reinterpret_cast<const f4*>(xr1 + koff + 4);
    }
  }
  __builtin_amdgcn_sched_barrier(0);

  // ---- stage W(head): each of 4 waves writes 8 of the 32 fragments ----
  const float* Wh = W + (size_t)head * NOUT * NIN;
  #pragma unroll
  for (int it = 0; it < 8; ++it) {
    const int frag = wid * 8 + it;
    const int n  = frag >> 2;
    const int kk = frag & 3;
    const float* src = Wh + (n * 16 + lr) * NIN + kk * 32 + lq * 8;
    f4 a = *reinterpret_cast<const f4*>(src);
    f4 b = *reinterpret_cast<const f4*>(src + 4);
    wtile[frag][lane] = cvt8(a, b);
  }
  __syncthreads();

  // Per tile: cvt+MFMA -> prefetch t+2 into freed slot -> store t.
#define TILE_BODY(xsC, T, PF)                                              \
  {                                                                        \
    f32x4 acc[8];                                                          \
    _Pragma("unroll")                                                      \
    for (int n = 0; n < 8; ++n) acc[n] = (f32x4){0.f, 0.f, 0.f, 0.f};      \
    _Pragma("unroll")                                                      \
    for (int kk = 0; kk < 4; ++kk) {                                       \
      short8 xv = cvt8(xsC[2*kk], xsC[2*kk+1]);                            \
      _Pragma("unroll")                                                    \
      for (int n = 0; n < 8; ++n)                                          \
        acc[n] = __builtin_amdgcn_mfma_f32_16x16x32_bf16(                  \
            wtile[n*4+kk][lane], xv, acc[n], 0, 0, 0);                     \
    }                                                                      \
    if (PF) {                                                              \
      const float* xrn = xr + (size_t)((T) + 2) * 64 * RSTR;               \
      _Pragma("unroll")                                                    \
      for (int kk = 0; kk < 4; ++kk) {                                     \
        const int koff = kk * 32 + lq * 8;                                 \
        xsC[2*kk]   = *reinterpret_cast<const f4*>(xrn + koff);            \
        xsC[2*kk+1] = *reinterpret_cast<const f4*>(xrn + koff + 4);        \
      }                                                                    \
      __builtin_amdgcn_sched_barrier(0);                                   \
    }                                                                      \
    float* dst = O + (size_t)(rowbase + (T) * 64 + lr) * RSTR + head*NOUT; \
    _Pragma("unroll")                                                      \
    for (int n = 0; n < 8; ++n)                                            \
      *reinterpret_cast<f4*>(dst + n * 16 + lq * 4) = acc[n];              \
  }

  TILE_BODY(xs0, 0, 1)
  TILE_BODY(xs1, 1, 1)
  TILE_BODY(xs0, 2, 1)
  TILE_BODY(xs1, 3, 1)
  TILE_BODY(xs0, 4, 1)
  TILE_BODY(xs1, 5, 1)
  TILE_BODY(xs0, 6, 0)
  TILE_BODY(xs1, 7, 0)
#undef TILE_BODY
}

extern "C" void kernel_launch(void* const* d_in, const int* in_sizes, int n_in,
                              void* d_out, int out_size, void* d_ws, size_t ws_size,
                              hipStream_t stream) {
  const float* X = (const float*)d_in[0];   // [8,2048,16,128] f32
  const float* W = (const float*)d_in[1];   // [16,128,128] f32
  float* O = (float*)d_out;                 // [8,2048,16,128] f32
  dim3 grid(BLOCKS_X, NHEAD);
  bdp_kernel<<<grid, dim3(256), 0, stream>>>(X, W, O);
}

// Round 12
// 55.770 us; speedup vs baseline: 1.7822x; 1.7822x over previous
//
#include <hip/hip_runtime.h>
#include <hip/hip_bf16.h>

typedef __attribute__((ext_vector_type(4))) float  f4;
typedef __attribute__((ext_vector_type(8))) short  short8;
typedef __attribute__((ext_vector_type(4))) float  f32x4;

static constexpr int NHEAD = 16;
static constexpr int NIN   = 128;
static constexpr int NOUT  = 128;
static constexpr int NROWS = 8 * 2048;          // B*S = 16384
static constexpr int RSTR  = NHEAD * NIN;       // 2048 floats per (b,s) row
static constexpr int TILES = 4;                 // 16-row tiles per wave
static constexpr int ROWS_PER_BLOCK = 128 * TILES;        // 512
static constexpr int BLOCKS_X = NROWS / ROWS_PER_BLOCK;   // 32 -> grid 32x16 = 512 WGs
// R6 config (52.3us best): 512thr WGs, 512 WGs total. Only change vs R6:
// per-tile cvt8 calls hoisted to tile top so all 8 slot-loads' first uses
// are ADJACENT -> scheduler clusters load issue+drain once per tile instead
// of paying ~4 serial HBM latencies per tile (R6 VGPR=60 proved per-kk sink).

static __device__ inline unsigned short f2bfu(float f) {
  union { __hip_bfloat16 h; unsigned short u; } v;
  v.h = __float2bfloat16(f);
  return v.u;
}

static __device__ inline short8 cvt8(f4 a, f4 b) {
  short8 r;
  r[0] = (short)f2bfu(a[0]); r[1] = (short)f2bfu(a[1]);
  r[2] = (short)f2bfu(a[2]); r[3] = (short)f2bfu(a[3]);
  r[4] = (short)f2bfu(b[0]); r[5] = (short)f2bfu(b[1]);
  r[6] = (short)f2bfu(b[2]); r[7] = (short)f2bfu(b[3]);
  return r;
}

__global__ __launch_bounds__(512, 4)   // VGPR cap 128 -> 2 WGs/CU (thread-capped)
void bdp_kernel(const float* __restrict__ X, const float* __restrict__ W,
                float* __restrict__ O) {
  // W(head) bf16 MFMA A-fragments, fragment-contiguous (0 bank conflicts):
  // frag = n*4 + kk; lane holds o = n*16 + (lane&15), k = kk*32 + (lane>>4)*8 + j.
  __shared__ short8 wtile[32][64];

  const int head = blockIdx.y;
  const int tid  = (int)threadIdx.x;
  const int lane = tid & 63;
  const int wid  = tid >> 6;      // 8 waves
  const int lr   = lane & 15;
  const int lq   = lane >> 4;

  const int rowbase = (int)blockIdx.x * ROWS_PER_BLOCK + wid * 16;
  const float* xr = X + (size_t)(rowbase + lr) * RSTR + head * NIN;

  // ---- issue tiles 0,1 X loads before W staging ----
  f4 xs0[8], xs1[8];              // two named slots (static indexing)
  #pragma unroll
  for (int kk = 0; kk < 4; ++kk) {
    const int koff = kk * 32 + lq * 8;
    xs0[2*kk]   = *reinterpret_cast<const f4*>(xr + koff);
    xs0[2*kk+1] = *reinterpret_cast<const f4*>(xr + koff + 4);
  }
  {
    const float* xr1 = xr + (size_t)128 * RSTR;
    #pragma unroll
    for (int kk = 0; kk < 4; ++kk) {
      const int koff = kk * 32 + lq * 8;
      xs1[2*kk]   = *reinterpret_cast<const f4*>(xr1 + koff);
      xs1[2*kk+1] = *reinterpret_cast<const f4*>(xr1 + koff + 4);
    }
  }
  __builtin_amdgcn_sched_barrier(0);

  // ---- stage W(head): each wave writes 4 of the 32 fragments ----
  const float* Wh = W + (size_t)head * NOUT * NIN;
  #pragma unroll
  for (int it = 0; it < 4; ++it) {
    const int frag = wid * 4 + it;
    const int n  = frag >> 2;
    const int kk = frag & 3;
    const float* src = Wh + (n * 16 + lr) * NIN + kk * 32 + lq * 8;
    f4 a = *reinterpret_cast<const f4*>(src);
    f4 b = *reinterpret_cast<const f4*>(src + 4);
    wtile[frag][lane] = cvt8(a, b);
  }
  __syncthreads();

  // Per tile: [hoisted cvt x4 -> one clustered load-drain] -> prefetch t+2
  // into the freed slot -> 32 MFMA on regs+LDS -> dwordx4 stores.
#define TILE_BODY(xsC, T, PF)                                              \
  {                                                                        \
    short8 xv[4];                                                          \
    _Pragma("unroll")                                                      \
    for (int kk = 0; kk < 4; ++kk)                                         \
      xv[kk] = cvt8(xsC[2*kk], xsC[2*kk+1]);                               \
    if (PF) {                                                              \
      const float* xrn = xr + (size_t)((T) + 2) * 128 * RSTR;              \
      _Pragma("unroll")                                                    \
      for (int kk = 0; kk < 4; ++kk) {                                     \
        const int koff = kk * 32 + lq * 8;                                 \
        xsC[2*kk]   = *reinterpret_cast<const f4*>(xrn + koff);            \
        xsC[2*kk+1] = *reinterpret_cast<const f4*>(xrn + koff + 4);        \
      }                                                                    \
      __builtin_amdgcn_sched_barrier(0);                                   \
    }                                                                      \
    f32x4 acc[8];                                                          \
    _Pragma("unroll")                                                      \
    for (int n = 0; n < 8; ++n) acc[n] = (f32x4){0.f, 0.f, 0.f, 0.f};      \
    _Pragma("unroll")                                                      \
    for (int kk = 0; kk < 4; ++kk) {                                       \
      _Pragma("unroll")                                                    \
      for (int n = 0; n < 8; ++n)                                          \
        acc[n] = __builtin_amdgcn_mfma_f32_16x16x32_bf16(                  \
            wtile[n*4+kk][lane], xv[kk], acc[n], 0, 0, 0);                 \
    }                                                                      \
    float* dst = O + (size_t)(rowbase + (T) * 128 + lr) * RSTR + head*NOUT;\
    _Pragma("unroll")                                                      \
    for (int n = 0; n < 8; ++n)                                            \
      *reinterpret_cast<f4*>(dst + n * 16 + lq * 4) = acc[n];              \
  }

  TILE_BODY(xs0, 0, 1)
  TILE_BODY(xs1, 1, 1)
  TILE_BODY(xs0, 2, 0)
  TILE_BODY(xs1, 3, 0)
#undef TILE_BODY
}

extern "C" void kernel_launch(void* const* d_in, const int* in_sizes, int n_in,
                              void* d_out, int out_size, void* d_ws, size_t ws_size,
                              hipStream_t stream) {
  const float* X = (const float*)d_in[0];   // [8,2048,16,128] f32
  const float* W = (const float*)d_in[1];   // [16,128,128] f32
  float* O = (float*)d_out;                 // [8,2048,16,128] f32
  dim3 grid(BLOCKS_X, NHEAD);
  bdp_kernel<<<grid, dim3(512), 0, stream>>>(X, W, O);
}